// Round 12
// baseline (86.263 us; speedup 1.0000x reference)
//
#include <hip/hip_runtime.h>
#include <math.h>

// CapsuleLayer dynamic routing, factored (u_hat never materialized):
//   s[b,m,:] = ((Sum_n e_n in[b,n,:]) / (Sum_n e_n)) @ W[:,m,:], e_n = exp(logit)
//   logit linear in per-pass wv updates -> cumulative wv, no per-n state.
//   Pass 0 (uniform softmax) = plain column sum, S = 2048.
//   exp via exp2: cum stores wv * log2(e); sweep uses exp2f (1 v_exp, no mul).
//
// R7/R8/R10/R11 all plateau 31-36us while trading L1/VALU/DS against TLP ->
// the structural constant was small m-groups: every CU re-swept the same
// 128 KB per pass per resident block. R12: 8 m per block, grid 256 = 1
// block/CU, TPB 1024 (16 waves):
//   - L1 touches/CU: 3 x 2048 lines (~2.5us), 1/4 of R10
//   - 5 barriers now amortized over 8 m (half the per-work barrier cost)
//   - tail = 128 lanes (2 waves parallel) merging 64 sub-partial sets
//   - launch_bounds(1024,2) -> 128-reg budget (measured rule 256/min_waves);
//     state ~95 regs -> no spill, HW runs 4 waves/EU
// Kept (all measured): dense loads (lane=(row,c4), 1 instr = 16 full rows),
// quad dot via DPP quad_perm 0xB1/0x4E (VALU), harvest via row_shl:4/8 only
// (sums land in lanes 0..3; NO xor16/32 - __shfl is ds_bpermute/DS pipe),
// sub-partials in red[64][176] (stride%32=16 -> float4 stores exactly 2-way
// = free), cheap pass-0 (e=1, m-independent), W in LDS stride 129,
// b = bx&63 pins batch b's 4 blocks to XCD b%8.

#define TPB 1024
#define SETS 176          // floats per partial-set: 8 m * 20 + pad; 176%32=16

typedef float vf2 __attribute__((ext_vector_type(2)));

// x + dpp_shuffled(x); bound_ctrl=true -> out-of-pattern lanes contribute 0
#define DPP_ADDF(x, ctrl) \
    ((x) + __int_as_float(__builtin_amdgcn_update_dpp( \
        0, __float_as_int(x), (ctrl), 0xF, 0xF, true)))
// quad_perm xor1 = 0xB1, xor2 = 0x4E; row_shl:4 = 0x104, row_shl:8 = 0x108

#define LOG2E 1.44269504088896f

__global__ __launch_bounds__(TPB, 2)
void capsule_routing_kernel(const float* __restrict__ in,
                            const float* __restrict__ W,
                            float* __restrict__ out)
{
    __shared__ float red[64 * SETS];  // [wave*4+rowof16][m*20 + {xc[16],S}]
    __shared__ float w_lds[16 * 129]; // W[d][m*16+c] (8 m), stride 129
    __shared__ float cum[128];        // cumulative wv[m][d] * LOG2E

    const int tid = threadIdx.x;
    const int w   = tid >> 6;         // 0..15
    const int l   = tid & 63;
    const int c4  = l & 3;            // dim-quarter of row
    const int rg  = l >> 4;           // row-of-16 within wave (0..3)
    const int b   = blockIdx.x & 63;
    const int m0  = (blockIdx.x >> 6) << 3;   // 4 m-groups of 8

    // dense: lane l reads float4 #(w*512 + g*64 + l); wave w owns rows
    // [w*128, w*128+128), g = 0..7
    const float4* __restrict__ inb4 =
        (const float4*)(in + ((size_t)b << 15)) + ((w << 9) + l);

    // stage W[:, m0:m0+8, :] (2048 floats) -> LDS, stride-129 rows.
    // Ordered before first use (tail) by pass-0's red barrier.
    #pragma unroll
    for (int k = 0; k < 2; ++k) {
        const int idx = tid + k * TPB;
        const int d = idx >> 7, r = idx & 127;
        w_lds[d * 129 + r] = W[(d << 9) + (m0 << 4) + r];
    }

    float cwv = 0.f;                  // tail lanes: raw cumulative wv

    for (int pass = 0; pass < 3; ++pass) {
        vf2 wva[8], wvb[8];
        if (pass) {
            #pragma unroll
            for (int m = 0; m < 8; ++m) {     // broadcast float4 LDS reads
                const float4 q = *(const float4*)&cum[(m << 4) + (c4 << 2)];
                wva[m].x = q.x; wva[m].y = q.y;
                wvb[m].x = q.z; wvb[m].y = q.w;
            }
        }

        vf2 xa[8], xb[8];
        float S[8];
        #pragma unroll
        for (int m = 0; m < 8; ++m) {
            xa[m].x = 0.f; xa[m].y = 0.f;
            xb[m].x = 0.f; xb[m].y = 0.f;
            S[m] = 0.f;
        }

        #pragma unroll 2
        for (int g = 0; g < 8; ++g) {
            const float4 f = inb4[g << 6];
            vf2 fa, fb;
            fa.x = f.x; fa.y = f.y; fb.x = f.z; fb.y = f.w;
            if (pass) {
                #pragma unroll
                for (int m = 0; m < 8; ++m) {
                    vf2 t = fa * wva[m] + fb * wvb[m];   // pk_mul + pk_fma
                    float d = t.x + t.y;
                    d = DPP_ADDF(d, 0xB1);               // quad-sum (VALU)
                    d = DPP_ADDF(d, 0x4E);
                    const float e = exp2f(d);            // logits pre-scaled
                    S[m] += e;
                    xa[m] += fa * e;
                    xb[m] += fb * e;
                }
            } else {                                     // e = 1, m-independent
                xa[0] += fa; xb[0] += fb;
            }
        }

        // harvest: row_shl:4 + row_shl:8 (VALU DPP) -> lanes 0..3 of each
        // row-of-16 hold its c4-group sums; float4 stores to red (2-way free)
        const int sbase = ((w << 2) + rg) * SETS;
        if (pass) {
            #pragma unroll
            for (int m = 0; m < 8; ++m) {
                float a0 = xa[m].x, a1 = xa[m].y, a2 = xb[m].x, a3 = xb[m].y;
                float ss = S[m];
                a0 = DPP_ADDF(a0, 0x104); a0 = DPP_ADDF(a0, 0x108);
                a1 = DPP_ADDF(a1, 0x104); a1 = DPP_ADDF(a1, 0x108);
                a2 = DPP_ADDF(a2, 0x104); a2 = DPP_ADDF(a2, 0x108);
                a3 = DPP_ADDF(a3, 0x104); a3 = DPP_ADDF(a3, 0x108);
                ss = DPP_ADDF(ss, 0x104); ss = DPP_ADDF(ss, 0x108);
                if ((l & 15) < 4)        // l&15 == c4
                    *(float4*)&red[sbase + m * 20 + (c4 << 2)] =
                        make_float4(a0, a1, a2, a3);
                if ((l & 15) == 0)
                    red[sbase + m * 20 + 16] = ss;
            }
        } else {
            float a0 = xa[0].x, a1 = xa[0].y, a2 = xb[0].x, a3 = xb[0].y;
            a0 = DPP_ADDF(a0, 0x104); a0 = DPP_ADDF(a0, 0x108);
            a1 = DPP_ADDF(a1, 0x104); a1 = DPP_ADDF(a1, 0x108);
            a2 = DPP_ADDF(a2, 0x104); a2 = DPP_ADDF(a2, 0x108);
            a3 = DPP_ADDF(a3, 0x104); a3 = DPP_ADDF(a3, 0x108);
            if ((l & 15) < 4)
                *(float4*)&red[sbase + (c4 << 2)] = make_float4(a0, a1, a2, a3);
        }
        __syncthreads();              // red ready (also orders W staging)

        // ---- tail: 2 waves (128 lanes), lane = (tm = tid>>4, tc = tid&15)
        if (tid < 128) {
            const int tm = tid >> 4;  // 0..7
            const int tc = tid & 15;
            float Stot, xtot = 0.f;
            if (pass) {
                Stot = 0.f;
                #pragma unroll 8
                for (int p = 0; p < 64; ++p) {
                    Stot += red[p * SETS + tm * 20 + 16];
                    xtot += red[p * SETS + tm * 20 + tc];
                }
            } else {
                Stot = 2048.f;
                #pragma unroll 8
                for (int p = 0; p < 64; ++p)
                    xtot += red[p * SETS + tc];   // m0 slot; same for all m
            }
            // s(tm,tc) = (1/S) Sum_d xtot(tm,d) * W[d][tm*16+tc]
            const int lbase = tid & 48;           // wave-local group base
            float s = 0.f;
            #pragma unroll
            for (int d = 0; d < 16; ++d)
                s += __shfl(xtot, lbase + d) * w_lds[d * 129 + (tm << 4) + tc];
            s /= Stot;
            float n2 = s * s;
            n2 += __shfl_xor(n2, 1);
            n2 += __shfl_xor(n2, 2);
            n2 += __shfl_xor(n2, 4);
            n2 += __shfl_xor(n2, 8);
            const float nr = sqrtf(n2);
            const float v  = s * (n2 / (1.f + n2)) / (nr + 1e-7f);
            if (pass < 2) {
                float wvv = 0.f;                  // wv(tm, d=tc)
                #pragma unroll
                for (int c2 = 0; c2 < 16; ++c2)
                    wvv += w_lds[tc * 129 + (tm << 4) + c2] * __shfl(v, lbase + c2);
                cwv += wvv;                       // raw accumulation
                cum[(tm << 4) + tc] = cwv * LOG2E;
            } else {
                out[((size_t)b << 9) + ((m0 + tm) << 4) + tc] = v;
            }
        }
        if (pass < 2) __syncthreads();            // cum ready; red reusable
    }
}

extern "C" void kernel_launch(void* const* d_in, const int* in_sizes, int n_in,
                              void* d_out, int out_size, void* d_ws, size_t ws_size,
                              hipStream_t stream) {
    (void)in_sizes; (void)n_in; (void)d_ws; (void)ws_size; (void)out_size;
    const float* in = (const float*)d_in[0];
    const float* W  = (const float*)d_in[1];
    float* out = (float*)d_out;
    hipLaunchKernelGGL(capsule_routing_kernel, dim3(256), dim3(TPB), 0, stream,
                       in, W, out);
}

// Round 13
// 79.232 us; speedup vs baseline: 1.0887x; 1.0887x over previous
//
#include <hip/hip_runtime.h>
#include <math.h>

// CapsuleLayer dynamic routing, factored (u_hat never materialized):
//   s[b,m,:] = ((Sum_n e_n in[b,n,:]) / (Sum_n e_n)) @ W[:,m,:], e_n = exp(logit)
//   logit linear in per-pass wv updates -> cumulative wv, no per-n state.
//   Pass 0 (uniform softmax) = plain column sum, S = 2048.
//   exp via exp2: cum stores wv * log2(e) (prescaled at tail, free).
//
// R13 = R10 (best measured, ~31us kernel) + exp-dedup. Model fit across
// R2/R5/R9 (VALUBusy x wall = 15-20us vs ~5us static VALU): v_exp_f32 at
// transcendental quarter-rate (~16cyc/wave64) x 4 redundant exps/quad/g
// (quad-uniform) = ~47% of sweep cycles — the one term untouched by five
// neutral restructures. Fix: each lane exps ONLY its own m (qp=l&3, 3
// cndmask select), rebroadcast e0..e3 via 4 quad_perm DPP movs (VALU).
// S becomes one per-lane accumulator (own m); row_shl:4/8 harvest still
// correct (lanes 4 apart share c4), lane c4 stores S[m=c4].
// Kept (all measured): dense loads (lane=(row,c4), 1 instr = 64 distinct
// 64B lines), quad dot via DPP quad_perm 0xB1/0x4E (VALU), harvest via
// row_shl:4/8 only (NO xor16/32 shfl — __shfl is ds_bpermute/DS pipe),
// sub-partials red[32][69] (conflict-free stores), single-wave tail,
// 2 barriers/pass (5 total), cheap pass-0, W in LDS stride 65,
// b = bx&63 pins batch to XCD b%8, launch_bounds(512,2) = 128-VGPR budget
// (measured rule VGPR=256/min_waves; grid caps residency at 2 blk/CU).

#define TPB 512

typedef float vf2 __attribute__((ext_vector_type(2)));

// x + dpp_shuffled(x); bound_ctrl=true -> out-of-pattern lanes contribute 0
#define DPP_ADDF(x, ctrl) \
    ((x) + __int_as_float(__builtin_amdgcn_update_dpp( \
        0, __float_as_int(x), (ctrl), 0xF, 0xF, true)))
// pure dpp mov (quad_perm broadcast)
#define DPP_MOVF(x, ctrl) \
    (__int_as_float(__builtin_amdgcn_update_dpp( \
        0, __float_as_int(x), (ctrl), 0xF, 0xF, true)))
// quad_perm xor1 = 0xB1, xor2 = 0x4E; row_shl:4 = 0x104, row_shl:8 = 0x108
// quad_perm bcast lane i: 0x00, 0x55, 0xAA, 0xFF

#define LOG2E 1.44269504088896f

__global__ __launch_bounds__(TPB, 2)
void capsule_routing_kernel(const float* __restrict__ in,
                            const float* __restrict__ W,
                            float* __restrict__ out)
{
    __shared__ float red[32 * 69];   // [wave*4+rowof16][m*17 + {S, xc[16]}]
    __shared__ float cum[64];        // cumulative wv[tmi][d] * LOG2E
    __shared__ float w_lds[16 * 65]; // W[d][tmi*16+c], stride 65

    const int tid = threadIdx.x;
    const int w   = tid >> 6;        // 0..7
    const int l   = tid & 63;
    const int c4  = l & 3;           // dim-quarter of row == own m (qp)
    const int rg  = l >> 4;          // row-of-16 within wave (0..3)
    const int b   = blockIdx.x & 63;
    const int m0  = (blockIdx.x >> 6) << 2;
    const bool qb0 = (l & 1) != 0;   // qp bit 0 (masks hoisted by compiler)
    const bool qb1 = (l & 2) != 0;   // qp bit 1

    // dense: lane l reads float4 #(w*1024 + g*64 + l); wave w owns rows
    // [w*256, w*256+256), g = 0..15
    const float4* __restrict__ inb4 =
        (const float4*)(in + ((size_t)b << 15)) + ((w << 10) + l);

    // stage W[:, m0:m0+4, :] (1024 floats) -> LDS, stride-65 rows.
    // Ordered before first use by pass-0's red barrier.
    #pragma unroll
    for (int k = 0; k < 2; ++k) {
        const int idx = tid + k * TPB;
        const int d = idx >> 6, r = idx & 63;
        w_lds[d * 65 + r] = W[(d << 9) + (m0 << 4) + r];
    }

    float cwv = 0.f;                 // tail-wave cumulative wv (lane = tmi,tc)

    for (int pass = 0; pass < 3; ++pass) {
        vf2 wva[4], wvb[4];
        if (pass) {
            const float4* cp = (const float4*)cum;   // 16-way broadcast reads
            #pragma unroll
            for (int m = 0; m < 4; ++m) {
                const float4 q = cp[(m << 2) + c4];  // cum[m*16 + c4*4 ..+3]
                wva[m].x = q.x; wva[m].y = q.y;
                wvb[m].x = q.z; wvb[m].y = q.w;
            }
        }

        vf2 xa[4], xb[4];
        float Sown = 0.f;            // S partial for m == c4 only
        #pragma unroll
        for (int m = 0; m < 4; ++m) {
            xa[m].x = 0.f; xa[m].y = 0.f;
            xb[m].x = 0.f; xb[m].y = 0.f;
        }

        #pragma unroll 2
        for (int g = 0; g < 16; ++g) {
            const float4 f = inb4[g << 6];
            vf2 fa, fb;
            fa.x = f.x; fa.y = f.y; fb.x = f.z; fb.y = f.w;
            if (pass) {
                float dm[4];
                #pragma unroll
                for (int m = 0; m < 4; ++m) {
                    vf2 t = fa * wva[m] + fb * wvb[m];   // pk_mul + pk_fma
                    float d = t.x + t.y;
                    d = DPP_ADDF(d, 0xB1);               // quad-sum (VALU)
                    d = DPP_ADDF(d, 0x4E);
                    dm[m] = d;
                }
                // one exp per lane (own m), then quad-broadcast all 4 e's
                const float dsel = qb1 ? (qb0 ? dm[3] : dm[2])
                                       : (qb0 ? dm[1] : dm[0]);
                const float eown = exp2f(dsel);          // logits prescaled
                const float e0 = DPP_MOVF(eown, 0x00);
                const float e1 = DPP_MOVF(eown, 0x55);
                const float e2 = DPP_MOVF(eown, 0xAA);
                const float e3 = DPP_MOVF(eown, 0xFF);
                Sown += eown;
                xa[0] += fa * e0; xb[0] += fb * e0;
                xa[1] += fa * e1; xb[1] += fb * e1;
                xa[2] += fa * e2; xb[2] += fb * e2;
                xa[3] += fa * e3; xb[3] += fb * e3;
            } else {                                     // e = 1, m-independent
                xa[0] += fa; xb[0] += fb;
            }
        }

        // harvest: row_shl:4 + row_shl:8 (VALU DPP) -> lanes 0..3 of each
        // row-of-16 hold its c4-group sums (for S: lanes 4 apart share c4,
        // so the same shifts sum S[m=c4] correctly). No cross-row shuffle.
        const int pbase = ((w << 2) + rg) * 69;
        if (pass) {
            float vals[16] = { xa[0].x, xa[0].y, xb[0].x, xb[0].y,
                               xa[1].x, xa[1].y, xb[1].x, xb[1].y,
                               xa[2].x, xa[2].y, xb[2].x, xb[2].y,
                               xa[3].x, xa[3].y, xb[3].x, xb[3].y };
            #pragma unroll
            for (int v = 0; v < 16; ++v) {
                float x = vals[v];
                x = DPP_ADDF(x, 0x104);   // lane i += lane i+4
                x = DPP_ADDF(x, 0x108);   // lane i += lane i+8
                vals[v] = x;
            }
            float ss = Sown;
            ss = DPP_ADDF(ss, 0x104);
            ss = DPP_ADDF(ss, 0x108);
            if ((l & 15) < 4) {           // l&15 == c4
                #pragma unroll
                for (int m = 0; m < 4; ++m) {
                    #pragma unroll
                    for (int j = 0; j < 4; ++j)
                        red[pbase + m * 17 + 1 + (c4 << 2) + j] = vals[(m << 2) + j];
                }
                red[pbase + c4 * 17] = ss;    // lane c4 owns S[m=c4]
            }
        } else {
            float vals[4] = { xa[0].x, xa[0].y, xb[0].x, xb[0].y };
            #pragma unroll
            for (int v = 0; v < 4; ++v) {
                float x = vals[v];
                x = DPP_ADDF(x, 0x104);
                x = DPP_ADDF(x, 0x108);
                vals[v] = x;
            }
            if ((l & 15) < 4) {
                #pragma unroll
                for (int j = 0; j < 4; ++j)
                    red[pbase + 1 + (c4 << 2) + j] = vals[j];
            }
        }
        __syncthreads();                  // red ready (also orders W staging)

        // ---- tail: wave 0 only. lane = (tmi = l>>4, tc = l&15) ----
        if (w == 0) {
            const int tmi = rg;           // l>>4
            const int tc  = l & 15;
            float Stot = 0.f, xtot = 0.f;
            if (pass) {
                #pragma unroll
                for (int p = 0; p < 32; ++p) {
                    Stot += red[p * 69 + tmi * 17];
                    xtot += red[p * 69 + tmi * 17 + 1 + tc];
                }
            } else {
                Stot = 2048.f;
                #pragma unroll
                for (int p = 0; p < 32; ++p)
                    xtot += red[p * 69 + 1 + tc];   // m0 slots; same for all m
            }
            // s(tmi,tc) = (1/S) Sum_d xtot(tmi,d) * W[d][tmi*16+tc]
            float s = 0.f;
            #pragma unroll
            for (int d = 0; d < 16; ++d)
                s += __shfl(xtot, (tmi << 4) + d) * w_lds[d * 65 + (tmi << 4) + tc];
            s /= Stot;
            float n2 = s * s;
            n2 += __shfl_xor(n2, 1);
            n2 += __shfl_xor(n2, 2);
            n2 += __shfl_xor(n2, 4);
            n2 += __shfl_xor(n2, 8);
            const float nr = sqrtf(n2);
            const float v  = s * (n2 / (1.f + n2)) / (nr + 1e-7f);
            if (pass < 2) {
                float wvv = 0.f;          // wv(tmi, d=tc)
                #pragma unroll
                for (int c2 = 0; c2 < 16; ++c2)
                    wvv += w_lds[tc * 65 + (tmi << 4) + c2] * __shfl(v, (tmi << 4) + c2);
                cwv += wvv;               // raw accumulation across passes
                cum[(tmi << 4) + tc] = cwv * LOG2E;   // prescale for exp2
            } else {
                out[((size_t)b << 9) + ((m0 + tmi) << 4) + tc] = v;
            }
        }
        if (pass < 2) __syncthreads();    // cum ready; red free for next pass
    }
}

extern "C" void kernel_launch(void* const* d_in, const int* in_sizes, int n_in,
                              void* d_out, int out_size, void* d_ws, size_t ws_size,
                              hipStream_t stream) {
    (void)in_sizes; (void)n_in; (void)d_ws; (void)ws_size; (void)out_size;
    const float* in = (const float*)d_in[0];
    const float* W  = (const float*)d_in[1];
    float* out = (float*)d_out;
    hipLaunchKernelGGL(capsule_routing_kernel, dim3(512), dim3(TPB), 0, stream,
                       in, W, out);
}